// Round 1
// baseline (7606.284 us; speedup 1.0000x reference)
//
#include <hip/hip_runtime.h>
#include <math.h>

// ---------------------------------------------------------------------------
// DisableGateLSTM R5: W-in-VGPR GEMM + DPP k-reduce + x-GEMM-under-barrier.
// 256 blocks x 512 threads, 1 block/CU. 4 groups x 64 blocks; group g owns
// chains [16g,16g+16); block j owns hidden units [8j,8j+8) = 32 gate rows.
//
// R5 changes vs R4 (4494us, LDS-pipe-bound: ~11Kcy/step of ds_read):
//  * Weights live in VGPRs (48 floats/thread, zero redundancy: thread =
//    (rg: 4 rows, s: 8 h-cols + 4 x-cols), C=16 chains). GEMM LDS reads
//    drop 96 -> 48 b128/thread/step. LDS 155KB -> ~70KB.
//  * 64-way k-split reduced 8x in-wave via 3 DPP adds (row_half_mirror,
//    quad_perm xor2, xor1 - involutions, all-lane result, VALU pipe which
//    has slack). Only 8 cross-wave partials -> 16KB conflict-free b128
//    scratch + 8 scalar reads/output.
//  * x-part GEMM (h-independent) runs BEFORE the gen poll: hides the
//    cnt/gen RMW chain + LLC visibility latency under ~0.6us of work.
//  * Gate phase widened 64 -> 128 threads (1 unit x 1 chain each).
// Cross-block h exchange: relaxed agent-scope atomics, cnt/gen monotonic
// barrier (R1-proven). Gates use exact libm expf/tanhf.
// ---------------------------------------------------------------------------

#define BATCH   64
#define SEQ     512
#define EMBED   256
#define HIDDEN  512
#define GD      768
#define CLASSES 4

#define NBLK    256
#define NTHR    512
#define GROUPS  4
#define GB      64
#define CPG     16
#define UPB     8
#define ROWS    32

// LDS strides (floats)
#define SHS  520   // sH chain stride: 512 + 8 (odd bank-quad phase per chain)
#define SXS  264   // sX chain stride: 256 + 8
#define PRS  68    // partial-scratch rank stride: 64 + 4 (ranks on distinct quads)

typedef unsigned long long __attribute__((may_alias)) ull_a;

union F2U { float f[2]; unsigned long long u; };

// Sum over each aligned 8-lane group via DPP involutions (VALU pipe, no LDS).
// half_mirror pairs (i,7-i), then quad xor2, xor1 -> every lane holds the sum.
__device__ __forceinline__ float dpp8_sum(float v) {
  int x;
  x = __builtin_amdgcn_update_dpp(0, __float_as_int(v), 0x141, 0xF, 0xF, false); // row_half_mirror
  v += __int_as_float(x);
  x = __builtin_amdgcn_update_dpp(0, __float_as_int(v), 0x4E,  0xF, 0xF, false); // quad_perm(2,3,0,1)
  v += __int_as_float(x);
  x = __builtin_amdgcn_update_dpp(0, __float_as_int(v), 0xB1,  0xF, 0xF, false); // quad_perm(1,0,3,2)
  v += __int_as_float(x);
  return v;
}

__global__ __launch_bounds__(NTHR, 1) void lstm_persistent(
    const int*   __restrict__ ids,
    const float* __restrict__ emb,
    const float* __restrict__ Wf, const float* __restrict__ bf,
    const float* __restrict__ Wi, const float* __restrict__ bi,
    const float* __restrict__ Wo, const float* __restrict__ bo,
    const float* __restrict__ Wc, const float* __restrict__ bc,
    const float* __restrict__ fcw,
    const float* __restrict__ fcb,
    float* __restrict__ out,
    float* __restrict__ ws)
{
  __shared__ __align__(16) float sH[CPG * SHS];      // 33.3 KB
  __shared__ __align__(16) float sX[CPG * SXS];      // 16.9 KB
  __shared__ __align__(16) float sPart[64 * PRS];    // 17.4 KB
  __shared__ float sG[ROWS][CPG];                    // 2 KB (also head scratch)
  __shared__ float sC[UPB][CPG];
  __shared__ float sM[UPB][CPG];
  __shared__ float sB[ROWS];

  const int tid = threadIdx.x;
  const int bid = blockIdx.x;
  const int g   = bid & 3;
  const int j   = bid >> 2;
  const int u0  = j * UPB;

  float*    hbufF   = ws;                                    // [2][64][512] f32
  ull_a*    hbufU   = (ull_a*)ws;                            // same, ull view
  float*    wmaxF   = ws + (size_t)2 * BATCH * HIDDEN;       // [64][512] f32
  ull_a*    wmaxU   = (ull_a*)wmaxF;
  unsigned* barArea = (unsigned*)(ws + (size_t)3 * BATCH * HIDDEN);
  unsigned* cnt     = barArea + g * 64;
  unsigned* gen     = barArea + 256 + g * 64;

  // ---- thread geometry ----
  // GEMM: rg = 4-row group (rows rg*4..rg*4+3, all one gate), s = k-slice
  // (h cols [8s,8s+8), x cols [4s,4s+4)). Lane = (rg<<3)|s_low -> the 8
  // s-values of a (wave,rg) sit in one aligned 8-lane DPP group.
  const int sl = tid & 7;
  const int wv = tid >> 6;
  const int s  = sl + wv * 8;          // 0..63
  const int rg = (tid >> 3) & 7;       // 0..7

  // ---- weights -> VGPRs, once (48 floats/thread, no redundancy) ----
  float4 wh[4][2], wx4[4];
  {
    const float* Wg = (rg < 2) ? Wf : (rg < 4) ? Wi : (rg < 6) ? Wo : Wc;
    const int ub = u0 + (rg & 1) * 4;
    #pragma unroll
    for (int ri = 0; ri < 4; ++ri) {
      const float* row = Wg + (size_t)(ub + ri) * GD;
      wh[ri][0] = *(const float4*)(row + s * 8);
      wh[ri][1] = *(const float4*)(row + s * 8 + 4);
      wx4[ri]   = *(const float4*)(row + HIDDEN + s * 4);
    }
  }
  if (tid < ROWS) {
    const float* bv = (tid < 8) ? bf : (tid < 16) ? bi : (tid < 24) ? bo : bc;
    sB[tid] = bv[u0 + (tid & 7)];
  }
  if (tid < UPB * CPG) {
    ((float*)sC)[tid] = 0.0f;
    ((float*)sM)[tid] = -3.402823e38f;
  }

  // staging mapping (chain-major, 32 lanes/chain)
  const int stg_c = tid >> 5;
  const int stg_s = tid & 31;
  const int bStg  = g * CPG + stg_c;

  const float* pH = sH + s * 8;        // + ci*SHS via imm offsets
  const float* pX = sX + s * 4;

  // prefetch x_0 into registers
  float4 rx0, rx1;
  {
    int id0 = ids[(size_t)bStg * SEQ];
    const float4* xs = (const float4*)(emb + (size_t)id0 * EMBED);
    rx0 = xs[stg_s * 2];
    rx1 = xs[stg_s * 2 + 1];
  }

  for (int t = 0; t < SEQ; ++t) {
    const int pb = t & 1;

    // ---- stage x_t (register -> LDS) ----
    {
      float* dx = sX + stg_c * SXS + stg_s * 8;
      *(float4*)dx = rx0;
      *(float4*)(dx + 4) = rx1;
    }
    __syncthreads();

    // ---- x-part GEMM (h-independent): runs UNDER the barrier wait ----
    float acc[4][16];
    #pragma unroll
    for (int ci = 0; ci < 16; ++ci) {
      float4 xv = *(const float4*)(pX + ci * SXS);
      #pragma unroll
      for (int ri = 0; ri < 4; ++ri) {
        float a;
        a = wx4[ri].x * xv.x;
        a = fmaf(wx4[ri].y, xv.y, a);
        a = fmaf(wx4[ri].z, xv.z, a);
        a = fmaf(wx4[ri].w, xv.w, a);
        acc[ri][ci] = a;
      }
    }

    // ---- wait for h_t (relaxed poll; no cache maintenance) ----
    if (tid == 0) {
      while (__hip_atomic_load(gen, __ATOMIC_RELAXED, __HIP_MEMORY_SCOPE_AGENT)
             < (unsigned)t)
        __builtin_amdgcn_s_sleep(1);
    }
    __atomic_signal_fence(__ATOMIC_ACQUIRE);
    __syncthreads();

    // ---- stage h_t via coherent loads ----
    {
      const ull_a* hs = hbufU + ((size_t)pb * BATCH + bStg) * (HIDDEN / 2);
      float* dh = sH + stg_c * SHS;
      #pragma unroll
      for (int kk = 0; kk < 8; ++kk) {
        unsigned long long v = __hip_atomic_load(hs + stg_s + kk * 32,
                                                 __ATOMIC_RELAXED,
                                                 __HIP_MEMORY_SCOPE_AGENT);
        *(ull_a*)(dh + 2 * stg_s + 64 * kk) = v;
      }
    }
    __syncthreads();

    // ---- h-part GEMM: W from VGPRs, h from LDS (8 distinct addrs/instr,
    //      2-way aliasing = free) ----
    #pragma unroll
    for (int ci = 0; ci < 16; ++ci) {
      float4 h0 = *(const float4*)(pH + ci * SHS);
      float4 h1 = *(const float4*)(pH + ci * SHS + 4);
      #pragma unroll
      for (int ri = 0; ri < 4; ++ri) {
        float a = acc[ri][ci];
        a = fmaf(wh[ri][0].x, h0.x, a);
        a = fmaf(wh[ri][0].y, h0.y, a);
        a = fmaf(wh[ri][0].z, h0.z, a);
        a = fmaf(wh[ri][0].w, h0.w, a);
        a = fmaf(wh[ri][1].x, h1.x, a);
        a = fmaf(wh[ri][1].y, h1.y, a);
        a = fmaf(wh[ri][1].z, h1.z, a);
        a = fmaf(wh[ri][1].w, h1.w, a);
        acc[ri][ci] = a;
      }
    }

    // ---- prefetch x_{t+1} (latency hides under reduce+gates) ----
    {
      const int tn = (t + 1 < SEQ) ? t + 1 : SEQ - 1;
      int idn = ids[(size_t)bStg * SEQ + tn];
      const float4* xs = (const float4*)(emb + (size_t)idn * EMBED);
      rx0 = xs[stg_s * 2];
      rx1 = xs[stg_s * 2 + 1];
    }

    // ---- in-wave 8x k-reduce on the VALU pipe (DPP), then one writer per
    //      8-lane group stores 64 partials (b128, ranks on distinct quads) ----
    #pragma unroll
    for (int ri = 0; ri < 4; ++ri)
      #pragma unroll
      for (int ci = 0; ci < 16; ++ci)
        acc[ri][ci] = dpp8_sum(acc[ri][ci]);
    if ((tid & 7) == 0) {
      float* dst = sPart + (tid >> 3) * PRS;   // rank = wv*8+rg
      #pragma unroll
      for (int ri = 0; ri < 4; ++ri) {
        *(float4*)(dst + ri * 16 + 0)  = make_float4(acc[ri][0],  acc[ri][1],  acc[ri][2],  acc[ri][3]);
        *(float4*)(dst + ri * 16 + 4)  = make_float4(acc[ri][4],  acc[ri][5],  acc[ri][6],  acc[ri][7]);
        *(float4*)(dst + ri * 16 + 8)  = make_float4(acc[ri][8],  acc[ri][9],  acc[ri][10], acc[ri][11]);
        *(float4*)(dst + ri * 16 + 12) = make_float4(acc[ri][12], acc[ri][13], acc[ri][14], acc[ri][15]);
      }
    }
    __syncthreads();

    // ---- cross-wave reduce (8 partials) + bias -> sG ----
    {
      const int rr  = tid >> 4;            // row 0..31
      const int ci2 = tid & 15;            // chain
      const int rg2 = rr >> 2;
      const int idx = (rr & 3) * 16 + ci2;
      float ssum = sB[rr];
      #pragma unroll
      for (int w = 0; w < 8; ++w)
        ssum += sPart[(w * 8 + rg2) * PRS + idx];
      sG[rr][ci2] = ssum;
    }
    __syncthreads();

    // ---- gates + state update + coherent h store (EXACT libm math) ----
    if (tid < 128) {
      const int u = tid & 7, ch = tid >> 3;
      float pf = sG[u][ch];
      float pi = sG[8 + u][ch];
      float po = sG[16 + u][ch];
      float pg = sG[24 + u][ch];
      float f  = 1.0f / (1.0f + expf(-pf));
      float i_ = 1.0f / (1.0f + expf(-pi));
      float o  = 1.0f / (1.0f + expf(-po));
      float gg = tanhf(pg);
      float cn = f * sC[u][ch] + i_ * gg;
      float h  = o * tanhf(cn);
      sC[u][ch] = cn;
      sM[u][ch] = fmaxf(sM[u][ch], h);
      __hip_atomic_store(
          hbufF + ((size_t)(pb ^ 1) * BATCH + g * CPG + ch) * HIDDEN + u0 + u,
          h, __ATOMIC_RELAXED, __HIP_MEMORY_SCOPE_AGENT);
    }
    __syncthreads();   // every wave drains vmcnt -> h stores coherence-visible

    // ---- arrival: monotonic count (never reset) ----
    if (tid == 0) {
      unsigned old = __hip_atomic_fetch_add(cnt, 1u, __ATOMIC_RELAXED,
                                            __HIP_MEMORY_SCOPE_AGENT);
      if (old == (unsigned)((t + 1) * GB - 1))
        __hip_atomic_store(gen, (unsigned)(t + 1), __ATOMIC_RELAXED,
                           __HIP_MEMORY_SCOPE_AGENT);
    }
  }

  // ---- publish running max (coherent), final barrier ----
  if (tid < 128) {
    const int u = tid & 7, ch = tid >> 3;
    __hip_atomic_store(wmaxF + (size_t)(g * CPG + ch) * HIDDEN + u0 + u,
                       sM[u][ch], __ATOMIC_RELAXED, __HIP_MEMORY_SCOPE_AGENT);
  }
  __syncthreads();
  if (tid == 0) {
    unsigned old = __hip_atomic_fetch_add(cnt, 1u, __ATOMIC_RELAXED,
                                          __HIP_MEMORY_SCOPE_AGENT);
    if (old == (unsigned)((SEQ + 1) * GB - 1))
      __hip_atomic_store(gen, (unsigned)(SEQ + 1), __ATOMIC_RELAXED,
                         __HIP_MEMORY_SCOPE_AGENT);
  }

  // ---- head GEMV on group-leader blocks ----
  if (j == 0) {
    if (tid == 0) {
      while (__hip_atomic_load(gen, __ATOMIC_RELAXED, __HIP_MEMORY_SCOPE_AGENT)
             < (unsigned)(SEQ + 1))
        __builtin_amdgcn_s_sleep(1);
    }
    __atomic_signal_fence(__ATOMIC_ACQUIRE);
    __syncthreads();

    const int ch = tid & 15, cls = (tid >> 4) & 3, us = tid >> 6;
    const ull_a* mrow = wmaxU + (size_t)(g * CPG + ch) * (HIDDEN / 2) + us * 32;
    const float* wrow = fcw + (size_t)cls * HIDDEN + us * 64;
    float sacc = 0.0f;
    for (int q = 0; q < 32; ++q) {
      F2U v;
      v.u = __hip_atomic_load(mrow + q, __ATOMIC_RELAXED,
                              __HIP_MEMORY_SCOPE_AGENT);
      sacc = fmaf(v.f[0], wrow[2 * q], sacc);
      sacc = fmaf(v.f[1], wrow[2 * q + 1], sacc);
    }
    float* red2 = &sG[0][0];
    red2[tid] = sacc;
    __syncthreads();
    if (tid < 64) {
      float tot = fcb[(tid >> 4) & 3];
      #pragma unroll
      for (int q = 0; q < 8; ++q) tot += red2[q * 64 + tid];
      out[(g * CPG + (tid & 15)) * CLASSES + ((tid >> 4) & 3)] = tot;
    }
  }
}

extern "C" void kernel_launch(void* const* d_in, const int* in_sizes, int n_in,
                              void* d_out, int out_size, void* d_ws, size_t ws_size,
                              hipStream_t stream) {
  const int*   ids = (const int*)  d_in[0];
  const float* emb = (const float*)d_in[1];
  const float* Wf  = (const float*)d_in[2];
  const float* bf  = (const float*)d_in[3];
  const float* Wi  = (const float*)d_in[4];
  const float* bi  = (const float*)d_in[5];
  const float* Wo  = (const float*)d_in[6];
  const float* bo  = (const float*)d_in[7];
  const float* Wc  = (const float*)d_in[8];
  const float* bc  = (const float*)d_in[9];
  const float* fcw = (const float*)d_in[10];
  const float* fcb = (const float*)d_in[11];

  // zero h0 (hbuf buffer 0) and the barrier counters
  hipMemsetAsync(d_ws, 0, (size_t)BATCH * HIDDEN * sizeof(float), stream);
  hipMemsetAsync((char*)d_ws + (size_t)3 * BATCH * HIDDEN * sizeof(float),
                 0, 4096, stream);

  lstm_persistent<<<dim3(NBLK), dim3(NTHR), 0, stream>>>(
      ids, emb, Wf, bf, Wi, bi, Wo, bo, Wc, bc, fcw, fcb,
      (float*)d_out, (float*)d_ws);
}

// Round 2
// 7559.061 us; speedup vs baseline: 1.0062x; 1.0062x over previous
//
#include <hip/hip_runtime.h>
#include <math.h>

// ---------------------------------------------------------------------------
// DisableGateLSTM R6: R5 + pinned register budget (the R5 fix).
// 256 blocks x 512 threads, 1 block/CU. 4 groups x 64 blocks; group g owns
// chains [16g,16g+16); block j owns hidden units [8j,8j+8) = 32 gate rows.
//
// R5 post-mortem: W-in-VGPR + DPP reduce was correct (absmax 0.0, bank
// conflicts halved) but the allocator capped at 128 VGPRs (occupancy
// heuristic targeting 4 waves/EU) and spilled ~24 dwords/thread/step to
// scratch: WRITE_SIZE 70MB->6.4GB, FETCH 108MB->4.4GB, dur 4494->7606us.
// LDS caps us at 1 block/CU = 2 waves/EU regardless, so waves_per_eu(1,2)
// legitimately unlocks the 256-VGPR budget; the ~160-reg live set
// (64 acc + 48 W + 8 prefetch + temps) then fits with zero spills.
//
//  * Weights live in VGPRs (48 floats/thread, zero redundancy: thread =
//    (rg: 4 rows, s: 8 h-cols + 4 x-cols), C=16 chains). GEMM LDS reads
//    are 48 b128/thread/step (vs R4's 96). LDS ~70KB.
//  * 64-way k-split reduced 8x in-wave via 3 DPP adds, 8 cross-wave
//    partials via conflict-free b128 scratch.
//  * x-part GEMM (h-independent) runs BEFORE the gen poll (hides barrier).
// Cross-block h exchange: relaxed agent-scope atomics, cnt/gen monotonic
// barrier (R1-proven). Gates use exact libm expf/tanhf.
// ---------------------------------------------------------------------------

#define BATCH   64
#define SEQ     512
#define EMBED   256
#define HIDDEN  512
#define GD      768
#define CLASSES 4

#define NBLK    256
#define NTHR    512
#define GROUPS  4
#define GB      64
#define CPG     16
#define UPB     8
#define ROWS    32

// LDS strides (floats)
#define SHS  520   // sH chain stride: 512 + 8 (odd bank-quad phase per chain)
#define SXS  264   // sX chain stride: 256 + 8
#define PRS  68    // partial-scratch rank stride: 64 + 4 (ranks on distinct quads)

typedef unsigned long long __attribute__((may_alias)) ull_a;

union F2U { float f[2]; unsigned long long u; };

// Sum over each aligned 8-lane group via DPP involutions (VALU pipe, no LDS).
// half_mirror pairs (i,7-i), then quad xor2, xor1 -> every lane holds the sum.
__device__ __forceinline__ float dpp8_sum(float v) {
  int x;
  x = __builtin_amdgcn_update_dpp(0, __float_as_int(v), 0x141, 0xF, 0xF, false); // row_half_mirror
  v += __int_as_float(x);
  x = __builtin_amdgcn_update_dpp(0, __float_as_int(v), 0x4E,  0xF, 0xF, false); // quad_perm(2,3,0,1)
  v += __int_as_float(x);
  x = __builtin_amdgcn_update_dpp(0, __float_as_int(v), 0xB1,  0xF, 0xF, false); // quad_perm(1,0,3,2)
  v += __int_as_float(x);
  return v;
}

__global__
__attribute__((amdgpu_waves_per_eu(1, 2)))   // 1 blk/CU (LDS-capped) = 2 waves/EU:
__launch_bounds__(NTHR)                      // allow up to 256 VGPRs, kill spills
void lstm_persistent(
    const int*   __restrict__ ids,
    const float* __restrict__ emb,
    const float* __restrict__ Wf, const float* __restrict__ bf,
    const float* __restrict__ Wi, const float* __restrict__ bi,
    const float* __restrict__ Wo, const float* __restrict__ bo,
    const float* __restrict__ Wc, const float* __restrict__ bc,
    const float* __restrict__ fcw,
    const float* __restrict__ fcb,
    float* __restrict__ out,
    float* __restrict__ ws)
{
  __shared__ __align__(16) float sH[CPG * SHS];      // 33.3 KB
  __shared__ __align__(16) float sX[CPG * SXS];      // 16.9 KB
  __shared__ __align__(16) float sPart[64 * PRS];    // 17.4 KB
  __shared__ float sG[ROWS][CPG];                    // 2 KB (also head scratch)
  __shared__ float sC[UPB][CPG];
  __shared__ float sM[UPB][CPG];
  __shared__ float sB[ROWS];

  const int tid = threadIdx.x;
  const int bid = blockIdx.x;
  const int g   = bid & 3;
  const int j   = bid >> 2;
  const int u0  = j * UPB;

  float*    hbufF   = ws;                                    // [2][64][512] f32
  ull_a*    hbufU   = (ull_a*)ws;                            // same, ull view
  float*    wmaxF   = ws + (size_t)2 * BATCH * HIDDEN;       // [64][512] f32
  ull_a*    wmaxU   = (ull_a*)wmaxF;
  unsigned* barArea = (unsigned*)(ws + (size_t)3 * BATCH * HIDDEN);
  unsigned* cnt     = barArea + g * 64;
  unsigned* gen     = barArea + 256 + g * 64;

  // ---- thread geometry ----
  // GEMM: rg = 4-row group (rows rg*4..rg*4+3, all one gate), s = k-slice
  // (h cols [8s,8s+8), x cols [4s,4s+4)). Lane = (rg<<3)|s_low -> the 8
  // s-values of a (wave,rg) sit in one aligned 8-lane DPP group.
  const int sl = tid & 7;
  const int wv = tid >> 6;
  const int s  = sl + wv * 8;          // 0..63
  const int rg = (tid >> 3) & 7;       // 0..7

  // ---- weights -> VGPRs, once (48 floats/thread, no redundancy) ----
  float4 wh[4][2], wx4[4];
  {
    const float* Wg = (rg < 2) ? Wf : (rg < 4) ? Wi : (rg < 6) ? Wo : Wc;
    const int ub = u0 + (rg & 1) * 4;
    #pragma unroll
    for (int ri = 0; ri < 4; ++ri) {
      const float* row = Wg + (size_t)(ub + ri) * GD;
      wh[ri][0] = *(const float4*)(row + s * 8);
      wh[ri][1] = *(const float4*)(row + s * 8 + 4);
      wx4[ri]   = *(const float4*)(row + HIDDEN + s * 4);
    }
  }
  if (tid < ROWS) {
    const float* bv = (tid < 8) ? bf : (tid < 16) ? bi : (tid < 24) ? bo : bc;
    sB[tid] = bv[u0 + (tid & 7)];
  }
  if (tid < UPB * CPG) {
    ((float*)sC)[tid] = 0.0f;
    ((float*)sM)[tid] = -3.402823e38f;
  }

  // staging mapping (chain-major, 32 lanes/chain)
  const int stg_c = tid >> 5;
  const int stg_s = tid & 31;
  const int bStg  = g * CPG + stg_c;

  const float* pH = sH + s * 8;        // + ci*SHS via imm offsets
  const float* pX = sX + s * 4;

  // prefetch x_0 into registers
  float4 rx0, rx1;
  {
    int id0 = ids[(size_t)bStg * SEQ];
    const float4* xs = (const float4*)(emb + (size_t)id0 * EMBED);
    rx0 = xs[stg_s * 2];
    rx1 = xs[stg_s * 2 + 1];
  }

  for (int t = 0; t < SEQ; ++t) {
    const int pb = t & 1;

    // ---- stage x_t (register -> LDS) ----
    {
      float* dx = sX + stg_c * SXS + stg_s * 8;
      *(float4*)dx = rx0;
      *(float4*)(dx + 4) = rx1;
    }
    __syncthreads();

    // ---- x-part GEMM (h-independent): runs UNDER the barrier wait ----
    float acc[4][16];
    #pragma unroll
    for (int ci = 0; ci < 16; ++ci) {
      float4 xv = *(const float4*)(pX + ci * SXS);
      #pragma unroll
      for (int ri = 0; ri < 4; ++ri) {
        float a;
        a = wx4[ri].x * xv.x;
        a = fmaf(wx4[ri].y, xv.y, a);
        a = fmaf(wx4[ri].z, xv.z, a);
        a = fmaf(wx4[ri].w, xv.w, a);
        acc[ri][ci] = a;
      }
    }

    // ---- wait for h_t (relaxed poll; no cache maintenance) ----
    if (tid == 0) {
      while (__hip_atomic_load(gen, __ATOMIC_RELAXED, __HIP_MEMORY_SCOPE_AGENT)
             < (unsigned)t)
        __builtin_amdgcn_s_sleep(1);
    }
    __atomic_signal_fence(__ATOMIC_ACQUIRE);
    __syncthreads();

    // ---- stage h_t via coherent loads ----
    {
      const ull_a* hs = hbufU + ((size_t)pb * BATCH + bStg) * (HIDDEN / 2);
      float* dh = sH + stg_c * SHS;
      #pragma unroll
      for (int kk = 0; kk < 8; ++kk) {
        unsigned long long v = __hip_atomic_load(hs + stg_s + kk * 32,
                                                 __ATOMIC_RELAXED,
                                                 __HIP_MEMORY_SCOPE_AGENT);
        *(ull_a*)(dh + 2 * stg_s + 64 * kk) = v;
      }
    }
    __syncthreads();

    // ---- h-part GEMM: W from VGPRs, h from LDS (8 distinct addrs/instr,
    //      2-way aliasing = free) ----
    #pragma unroll
    for (int ci = 0; ci < 16; ++ci) {
      float4 h0 = *(const float4*)(pH + ci * SHS);
      float4 h1 = *(const float4*)(pH + ci * SHS + 4);
      #pragma unroll
      for (int ri = 0; ri < 4; ++ri) {
        float a = acc[ri][ci];
        a = fmaf(wh[ri][0].x, h0.x, a);
        a = fmaf(wh[ri][0].y, h0.y, a);
        a = fmaf(wh[ri][0].z, h0.z, a);
        a = fmaf(wh[ri][0].w, h0.w, a);
        a = fmaf(wh[ri][1].x, h1.x, a);
        a = fmaf(wh[ri][1].y, h1.y, a);
        a = fmaf(wh[ri][1].z, h1.z, a);
        a = fmaf(wh[ri][1].w, h1.w, a);
        acc[ri][ci] = a;
      }
    }

    // ---- prefetch x_{t+1} (latency hides under reduce+gates) ----
    {
      const int tn = (t + 1 < SEQ) ? t + 1 : SEQ - 1;
      int idn = ids[(size_t)bStg * SEQ + tn];
      const float4* xs = (const float4*)(emb + (size_t)idn * EMBED);
      rx0 = xs[stg_s * 2];
      rx1 = xs[stg_s * 2 + 1];
    }

    // ---- in-wave 8x k-reduce on the VALU pipe (DPP), then one writer per
    //      8-lane group stores 64 partials (b128, ranks on distinct quads) ----
    #pragma unroll
    for (int ri = 0; ri < 4; ++ri)
      #pragma unroll
      for (int ci = 0; ci < 16; ++ci)
        acc[ri][ci] = dpp8_sum(acc[ri][ci]);
    if ((tid & 7) == 0) {
      float* dst = sPart + (tid >> 3) * PRS;   // rank = wv*8+rg
      #pragma unroll
      for (int ri = 0; ri < 4; ++ri) {
        *(float4*)(dst + ri * 16 + 0)  = make_float4(acc[ri][0],  acc[ri][1],  acc[ri][2],  acc[ri][3]);
        *(float4*)(dst + ri * 16 + 4)  = make_float4(acc[ri][4],  acc[ri][5],  acc[ri][6],  acc[ri][7]);
        *(float4*)(dst + ri * 16 + 8)  = make_float4(acc[ri][8],  acc[ri][9],  acc[ri][10], acc[ri][11]);
        *(float4*)(dst + ri * 16 + 12) = make_float4(acc[ri][12], acc[ri][13], acc[ri][14], acc[ri][15]);
      }
    }
    __syncthreads();

    // ---- cross-wave reduce (8 partials) + bias -> sG ----
    {
      const int rr  = tid >> 4;            // row 0..31
      const int ci2 = tid & 15;            // chain
      const int rg2 = rr >> 2;
      const int idx = (rr & 3) * 16 + ci2;
      float ssum = sB[rr];
      #pragma unroll
      for (int w = 0; w < 8; ++w)
        ssum += sPart[(w * 8 + rg2) * PRS + idx];
      sG[rr][ci2] = ssum;
    }
    __syncthreads();

    // ---- gates + state update + coherent h store (EXACT libm math) ----
    if (tid < 128) {
      const int u = tid & 7, ch = tid >> 3;
      float pf = sG[u][ch];
      float pi = sG[8 + u][ch];
      float po = sG[16 + u][ch];
      float pg = sG[24 + u][ch];
      float f  = 1.0f / (1.0f + expf(-pf));
      float i_ = 1.0f / (1.0f + expf(-pi));
      float o  = 1.0f / (1.0f + expf(-po));
      float gg = tanhf(pg);
      float cn = f * sC[u][ch] + i_ * gg;
      float h  = o * tanhf(cn);
      sC[u][ch] = cn;
      sM[u][ch] = fmaxf(sM[u][ch], h);
      __hip_atomic_store(
          hbufF + ((size_t)(pb ^ 1) * BATCH + g * CPG + ch) * HIDDEN + u0 + u,
          h, __ATOMIC_RELAXED, __HIP_MEMORY_SCOPE_AGENT);
    }
    __syncthreads();   // every wave drains vmcnt -> h stores coherence-visible

    // ---- arrival: monotonic count (never reset) ----
    if (tid == 0) {
      unsigned old = __hip_atomic_fetch_add(cnt, 1u, __ATOMIC_RELAXED,
                                            __HIP_MEMORY_SCOPE_AGENT);
      if (old == (unsigned)((t + 1) * GB - 1))
        __hip_atomic_store(gen, (unsigned)(t + 1), __ATOMIC_RELAXED,
                           __HIP_MEMORY_SCOPE_AGENT);
    }
  }

  // ---- publish running max (coherent), final barrier ----
  if (tid < 128) {
    const int u = tid & 7, ch = tid >> 3;
    __hip_atomic_store(wmaxF + (size_t)(g * CPG + ch) * HIDDEN + u0 + u,
                       sM[u][ch], __ATOMIC_RELAXED, __HIP_MEMORY_SCOPE_AGENT);
  }
  __syncthreads();
  if (tid == 0) {
    unsigned old = __hip_atomic_fetch_add(cnt, 1u, __ATOMIC_RELAXED,
                                          __HIP_MEMORY_SCOPE_AGENT);
    if (old == (unsigned)((SEQ + 1) * GB - 1))
      __hip_atomic_store(gen, (unsigned)(SEQ + 1), __ATOMIC_RELAXED,
                         __HIP_MEMORY_SCOPE_AGENT);
  }

  // ---- head GEMV on group-leader blocks ----
  if (j == 0) {
    if (tid == 0) {
      while (__hip_atomic_load(gen, __ATOMIC_RELAXED, __HIP_MEMORY_SCOPE_AGENT)
             < (unsigned)(SEQ + 1))
        __builtin_amdgcn_s_sleep(1);
    }
    __atomic_signal_fence(__ATOMIC_ACQUIRE);
    __syncthreads();

    const int ch = tid & 15, cls = (tid >> 4) & 3, us = tid >> 6;
    const ull_a* mrow = wmaxU + (size_t)(g * CPG + ch) * (HIDDEN / 2) + us * 32;
    const float* wrow = fcw + (size_t)cls * HIDDEN + us * 64;
    float sacc = 0.0f;
    for (int q = 0; q < 32; ++q) {
      F2U v;
      v.u = __hip_atomic_load(mrow + q, __ATOMIC_RELAXED,
                              __HIP_MEMORY_SCOPE_AGENT);
      sacc = fmaf(v.f[0], wrow[2 * q], sacc);
      sacc = fmaf(v.f[1], wrow[2 * q + 1], sacc);
    }
    float* red2 = &sG[0][0];
    red2[tid] = sacc;
    __syncthreads();
    if (tid < 64) {
      float tot = fcb[(tid >> 4) & 3];
      #pragma unroll
      for (int q = 0; q < 8; ++q) tot += red2[q * 64 + tid];
      out[(g * CPG + (tid & 15)) * CLASSES + ((tid >> 4) & 3)] = tot;
    }
  }
}

extern "C" void kernel_launch(void* const* d_in, const int* in_sizes, int n_in,
                              void* d_out, int out_size, void* d_ws, size_t ws_size,
                              hipStream_t stream) {
  const int*   ids = (const int*)  d_in[0];
  const float* emb = (const float*)d_in[1];
  const float* Wf  = (const float*)d_in[2];
  const float* bf  = (const float*)d_in[3];
  const float* Wi  = (const float*)d_in[4];
  const float* bi  = (const float*)d_in[5];
  const float* Wo  = (const float*)d_in[6];
  const float* bo  = (const float*)d_in[7];
  const float* Wc  = (const float*)d_in[8];
  const float* bc  = (const float*)d_in[9];
  const float* fcw = (const float*)d_in[10];
  const float* fcb = (const float*)d_in[11];

  // zero h0 (hbuf buffer 0) and the barrier counters
  hipMemsetAsync(d_ws, 0, (size_t)BATCH * HIDDEN * sizeof(float), stream);
  hipMemsetAsync((char*)d_ws + (size_t)3 * BATCH * HIDDEN * sizeof(float),
                 0, 4096, stream);

  lstm_persistent<<<dim3(NBLK), dim3(NTHR), 0, stream>>>(
      ids, emb, Wf, bf, Wi, bi, Wo, bo, Wc, bc, fcw, fcb,
      (float*)d_out, (float*)d_ws);
}

// Round 5
// 4249.430 us; speedup vs baseline: 1.7900x; 1.7788x over previous
//
#include <hip/hip_runtime.h>
#include <math.h>

// ---------------------------------------------------------------------------
// DisableGateLSTM R9: spill-free by construction (fits the 128-VGPR cap).
// 256 blocks x 512 threads, 1 block/CU. 4 groups x 64 blocks; group g owns
// chains [16g,16g+16); block j owns hidden units [8j,8j+8) = 32 gate rows.
//
// History: R5/R6 (W-in-VGPR + DPP k-reduce) were algorithmically right but
// the backend capped VGPRs at 128 and spilled ~24 dwords/thread/step
// (WRITE 70MB->6.4GB, dur 4494->7606). Budget levers failed: launch_bounds
// min-waves (R5) and amdgpu_waves_per_eu(1,2) (R6) both ignored; the
// LDS-pad-past-80KiB probe (R7/R8) never ran (container failed twice,
// twice). R9 removes the dependency on any budget lever: fuse the GEMM
// per-chain so the accumulator live set is 4 regs instead of 64.
//   peak live ~= 48 W + 8 prefetch + 12 slice temps + ~20 addr ~= 90 < 128.
// Per chain ci: {load x(1xb128)+h(2xb128), 12 FMA x 4 rows, dpp8_sum,
// writer-lane b32 partial stores}. FMA order per output unchanged from the
// verified R6 (x.x..w then h0..h1) -> numerics exact. Trade-off accepted:
// x-GEMM no longer hides under the gen poll (<~1us/step).
//
//  * Weights in VGPRs (48 floats/thread, zero redundancy: thread =
//    (rg: 4 rows, s: 12-wide k-slice), C=16 chains). 48 b128 LDS reads
//    per thread per step (R4 had 96).
//  * 64-way k-split folded 8x in-wave via 3 DPP adds (row_half_mirror,
//    quad_perm xor2, xor1); 8 cross-wave partials via sPart (PRS=68:
//    ranks on distinct bank quads -- writers rank+1 apart -> banks 4
//    apart -> conflict-free. Do NOT change PRS without re-deriving).
// Cross-block h exchange: relaxed agent-scope atomics, cnt/gen monotonic
// barrier (R1-proven). Gates use exact libm expf/tanhf.
// ---------------------------------------------------------------------------

#define BATCH   64
#define SEQ     512
#define EMBED   256
#define HIDDEN  512
#define GD      768
#define CLASSES 4

#define NBLK    256
#define NTHR    512
#define GROUPS  4
#define GB      64
#define CPG     16
#define UPB     8
#define ROWS    32

// LDS strides (floats)
#define SHS  520   // sH chain stride: 512 + 8 (odd bank-quad phase per chain)
#define SXS  264   // sX chain stride: 256 + 8
#define PRS  68    // partial-scratch rank stride: 64 + 4 (ranks on distinct quads)

typedef unsigned long long __attribute__((may_alias)) ull_a;

union F2U { float f[2]; unsigned long long u; };

// Sum over each aligned 8-lane group via DPP involutions (VALU pipe, no LDS).
// half_mirror pairs (i,7-i), then quad xor2, xor1 -> every lane holds the sum.
__device__ __forceinline__ float dpp8_sum(float v) {
  int x;
  x = __builtin_amdgcn_update_dpp(0, __float_as_int(v), 0x141, 0xF, 0xF, false); // row_half_mirror
  v += __int_as_float(x);
  x = __builtin_amdgcn_update_dpp(0, __float_as_int(v), 0x4E,  0xF, 0xF, false); // quad_perm(2,3,0,1)
  v += __int_as_float(x);
  x = __builtin_amdgcn_update_dpp(0, __float_as_int(v), 0xB1,  0xF, 0xF, false); // quad_perm(1,0,3,2)
  v += __int_as_float(x);
  return v;
}

__global__ __launch_bounds__(NTHR) void lstm_persistent(
    const int*   __restrict__ ids,
    const float* __restrict__ emb,
    const float* __restrict__ Wf, const float* __restrict__ bf,
    const float* __restrict__ Wi, const float* __restrict__ bi,
    const float* __restrict__ Wo, const float* __restrict__ bo,
    const float* __restrict__ Wc, const float* __restrict__ bc,
    const float* __restrict__ fcw,
    const float* __restrict__ fcb,
    float* __restrict__ out,
    float* __restrict__ ws)
{
  __shared__ __align__(16) float sH[CPG * SHS];      // 33.3 KB
  __shared__ __align__(16) float sX[CPG * SXS];      // 16.9 KB
  __shared__ __align__(16) float sPart[64 * PRS];    // 17.4 KB
  __shared__ float sG[ROWS][CPG];                    // 2 KB (also head scratch)
  __shared__ float sC[UPB][CPG];
  __shared__ float sM[UPB][CPG];
  __shared__ float sB[ROWS];

  const int tid = threadIdx.x;
  const int bid = blockIdx.x;
  const int g   = bid & 3;
  const int j   = bid >> 2;
  const int u0  = j * UPB;

  float*    hbufF   = ws;                                    // [2][64][512] f32
  ull_a*    hbufU   = (ull_a*)ws;                            // same, ull view
  float*    wmaxF   = ws + (size_t)2 * BATCH * HIDDEN;       // [64][512] f32
  ull_a*    wmaxU   = (ull_a*)wmaxF;
  unsigned* barArea = (unsigned*)(ws + (size_t)3 * BATCH * HIDDEN);
  unsigned* cnt     = barArea + g * 64;
  unsigned* gen     = barArea + 256 + g * 64;

  // ---- thread geometry ----
  // GEMM: rg = 4-row group (rows rg*4..rg*4+3, all one gate), s = k-slice
  // (h cols [8s,8s+8), x cols [4s,4s+4)). Lane = (rg<<3)|s_low -> the 8
  // s-values of a (wave,rg) sit in one aligned 8-lane DPP group.
  const int sl = tid & 7;
  const int wv = tid >> 6;
  const int s  = sl + wv * 8;          // 0..63
  const int rg = (tid >> 3) & 7;       // 0..7

  // ---- weights -> VGPRs, once (48 floats/thread, no redundancy) ----
  float4 wh[4][2], wx4[4];
  {
    const float* Wg = (rg < 2) ? Wf : (rg < 4) ? Wi : (rg < 6) ? Wo : Wc;
    const int ub = u0 + (rg & 1) * 4;
    #pragma unroll
    for (int ri = 0; ri < 4; ++ri) {
      const float* row = Wg + (size_t)(ub + ri) * GD;
      wh[ri][0] = *(const float4*)(row + s * 8);
      wh[ri][1] = *(const float4*)(row + s * 8 + 4);
      wx4[ri]   = *(const float4*)(row + HIDDEN + s * 4);
    }
  }
  if (tid < ROWS) {
    const float* bv = (tid < 8) ? bf : (tid < 16) ? bi : (tid < 24) ? bo : bc;
    sB[tid] = bv[u0 + (tid & 7)];
  }
  if (tid < UPB * CPG) {
    ((float*)sC)[tid] = 0.0f;
    ((float*)sM)[tid] = -3.402823e38f;
  }

  // staging mapping (chain-major, 32 lanes/chain)
  const int stg_c = tid >> 5;
  const int stg_s = tid & 31;
  const int bStg  = g * CPG + stg_c;

  const float* pH = sH + s * 8;        // + ci*SHS via imm offsets
  const float* pX = sX + s * 4;

  // prefetch x_0 into registers
  float4 rx0, rx1;
  {
    int id0 = ids[(size_t)bStg * SEQ];
    const float4* xs = (const float4*)(emb + (size_t)id0 * EMBED);
    rx0 = xs[stg_s * 2];
    rx1 = xs[stg_s * 2 + 1];
  }

  for (int t = 0; t < SEQ; ++t) {
    const int pb = t & 1;

    // ---- stage x_t (register -> LDS); visible after the poll barrier ----
    {
      float* dx = sX + stg_c * SXS + stg_s * 8;
      *(float4*)dx = rx0;
      *(float4*)(dx + 4) = rx1;
    }

    // ---- wait for h_t (relaxed poll; no cache maintenance) ----
    if (tid == 0) {
      while (__hip_atomic_load(gen, __ATOMIC_RELAXED, __HIP_MEMORY_SCOPE_AGENT)
             < (unsigned)t)
        __builtin_amdgcn_s_sleep(1);
    }
    __atomic_signal_fence(__ATOMIC_ACQUIRE);
    __syncthreads();

    // ---- stage h_t via coherent loads ----
    {
      const ull_a* hs = hbufU + ((size_t)pb * BATCH + bStg) * (HIDDEN / 2);
      float* dh = sH + stg_c * SHS;
      #pragma unroll
      for (int kk = 0; kk < 8; ++kk) {
        unsigned long long v = __hip_atomic_load(hs + stg_s + kk * 32,
                                                 __ATOMIC_RELAXED,
                                                 __HIP_MEMORY_SCOPE_AGENT);
        *(ull_a*)(dh + 2 * stg_s + 64 * kk) = v;
      }
    }
    __syncthreads();

    // ---- fused GEMM + in-wave DPP k-reduce + partial store, per chain.
    //      Accumulator live set = 4 regs; W stays in VGPRs; h/x from LDS
    //      (8 distinct addrs/instr, 2-way aliasing = free). FMA order per
    //      output identical to R6 (x.x..w then h0..h1). ----
    #pragma unroll
    for (int ci = 0; ci < 16; ++ci) {
      float4 xv = *(const float4*)(pX + ci * SXS);
      float4 h0 = *(const float4*)(pH + ci * SHS);
      float4 h1 = *(const float4*)(pH + ci * SHS + 4);
      float a[4];
      #pragma unroll
      for (int ri = 0; ri < 4; ++ri) {
        float t0;
        t0 = wx4[ri].x * xv.x;
        t0 = fmaf(wx4[ri].y, xv.y, t0);
        t0 = fmaf(wx4[ri].z, xv.z, t0);
        t0 = fmaf(wx4[ri].w, xv.w, t0);
        t0 = fmaf(wh[ri][0].x, h0.x, t0);
        t0 = fmaf(wh[ri][0].y, h0.y, t0);
        t0 = fmaf(wh[ri][0].z, h0.z, t0);
        t0 = fmaf(wh[ri][0].w, h0.w, t0);
        t0 = fmaf(wh[ri][1].x, h1.x, t0);
        t0 = fmaf(wh[ri][1].y, h1.y, t0);
        t0 = fmaf(wh[ri][1].z, h1.z, t0);
        t0 = fmaf(wh[ri][1].w, h1.w, t0);
        a[ri] = dpp8_sum(t0);
      }
      if ((tid & 7) == 0) {
        // rank = wv*8+rg; within a wave ranks differ by 1 -> addresses
        // differ by PRS=68 -> banks 4 apart -> 8 distinct banks, no conflict.
        float* dst = sPart + (tid >> 3) * PRS + ci;
        dst[0]  = a[0];
        dst[16] = a[1];
        dst[32] = a[2];
        dst[48] = a[3];
      }
    }

    // ---- prefetch x_{t+1} (latency hides under reduce+gates) ----
    {
      const int tn = (t + 1 < SEQ) ? t + 1 : SEQ - 1;
      int idn = ids[(size_t)bStg * SEQ + tn];
      const float4* xs = (const float4*)(emb + (size_t)idn * EMBED);
      rx0 = xs[stg_s * 2];
      rx1 = xs[stg_s * 2 + 1];
    }
    __syncthreads();

    // ---- cross-wave reduce (8 partials) + bias -> sG ----
    {
      const int rr  = tid >> 4;            // row 0..31
      const int ci2 = tid & 15;            // chain
      const int rg2 = rr >> 2;
      const int idx = (rr & 3) * 16 + ci2;
      float ssum = sB[rr];
      #pragma unroll
      for (int w = 0; w < 8; ++w)
        ssum += sPart[(w * 8 + rg2) * PRS + idx];
      sG[rr][ci2] = ssum;
    }
    __syncthreads();

    // ---- gates + state update + coherent h store (EXACT libm math) ----
    if (tid < 128) {
      const int u = tid & 7, ch = tid >> 3;
      float pf = sG[u][ch];
      float pi = sG[8 + u][ch];
      float po = sG[16 + u][ch];
      float pg = sG[24 + u][ch];
      float f  = 1.0f / (1.0f + expf(-pf));
      float i_ = 1.0f / (1.0f + expf(-pi));
      float o  = 1.0f / (1.0f + expf(-po));
      float gg = tanhf(pg);
      float cn = f * sC[u][ch] + i_ * gg;
      float h  = o * tanhf(cn);
      sC[u][ch] = cn;
      sM[u][ch] = fmaxf(sM[u][ch], h);
      __hip_atomic_store(
          hbufF + ((size_t)(pb ^ 1) * BATCH + g * CPG + ch) * HIDDEN + u0 + u,
          h, __ATOMIC_RELAXED, __HIP_MEMORY_SCOPE_AGENT);
    }
    __syncthreads();   // every wave drains vmcnt -> h stores coherence-visible

    // ---- arrival: monotonic count (never reset) ----
    if (tid == 0) {
      unsigned old = __hip_atomic_fetch_add(cnt, 1u, __ATOMIC_RELAXED,
                                            __HIP_MEMORY_SCOPE_AGENT);
      if (old == (unsigned)((t + 1) * GB - 1))
        __hip_atomic_store(gen, (unsigned)(t + 1), __ATOMIC_RELAXED,
                           __HIP_MEMORY_SCOPE_AGENT);
    }
  }

  // ---- publish running max (coherent), final barrier ----
  if (tid < 128) {
    const int u = tid & 7, ch = tid >> 3;
    __hip_atomic_store(wmaxF + (size_t)(g * CPG + ch) * HIDDEN + u0 + u,
                       sM[u][ch], __ATOMIC_RELAXED, __HIP_MEMORY_SCOPE_AGENT);
  }
  __syncthreads();
  if (tid == 0) {
    unsigned old = __hip_atomic_fetch_add(cnt, 1u, __ATOMIC_RELAXED,
                                          __HIP_MEMORY_SCOPE_AGENT);
    if (old == (unsigned)((SEQ + 1) * GB - 1))
      __hip_atomic_store(gen, (unsigned)(SEQ + 1), __ATOMIC_RELAXED,
                         __HIP_MEMORY_SCOPE_AGENT);
  }

  // ---- head GEMV on group-leader blocks ----
  if (j == 0) {
    if (tid == 0) {
      while (__hip_atomic_load(gen, __ATOMIC_RELAXED, __HIP_MEMORY_SCOPE_AGENT)
             < (unsigned)(SEQ + 1))
        __builtin_amdgcn_s_sleep(1);
    }
    __atomic_signal_fence(__ATOMIC_ACQUIRE);
    __syncthreads();

    const int ch = tid & 15, cls = (tid >> 4) & 3, us = tid >> 6;
    const ull_a* mrow = wmaxU + (size_t)(g * CPG + ch) * (HIDDEN / 2) + us * 32;
    const float* wrow = fcw + (size_t)cls * HIDDEN + us * 64;
    float sacc = 0.0f;
    for (int q = 0; q < 32; ++q) {
      F2U v;
      v.u = __hip_atomic_load(mrow + q, __ATOMIC_RELAXED,
                              __HIP_MEMORY_SCOPE_AGENT);
      sacc = fmaf(v.f[0], wrow[2 * q], sacc);
      sacc = fmaf(v.f[1], wrow[2 * q + 1], sacc);
    }
    float* red2 = &sG[0][0];
    red2[tid] = sacc;
    __syncthreads();
    if (tid < 64) {
      float tot = fcb[(tid >> 4) & 3];
      #pragma unroll
      for (int q = 0; q < 8; ++q) tot += red2[q * 64 + tid];
      out[(g * CPG + (tid & 15)) * CLASSES + ((tid >> 4) & 3)] = tot;
    }
  }
}

extern "C" void kernel_launch(void* const* d_in, const int* in_sizes, int n_in,
                              void* d_out, int out_size, void* d_ws, size_t ws_size,
                              hipStream_t stream) {
  const int*   ids = (const int*)  d_in[0];
  const float* emb = (const float*)d_in[1];
  const float* Wf  = (const float*)d_in[2];
  const float* bf  = (const float*)d_in[3];
  const float* Wi  = (const float*)d_in[4];
  const float* bi  = (const float*)d_in[5];
  const float* Wo  = (const float*)d_in[6];
  const float* bo  = (const float*)d_in[7];
  const float* Wc  = (const float*)d_in[8];
  const float* bc  = (const float*)d_in[9];
  const float* fcw = (const float*)d_in[10];
  const float* fcb = (const float*)d_in[11];

  // zero h0 (hbuf buffer 0) and the barrier counters
  hipMemsetAsync(d_ws, 0, (size_t)BATCH * HIDDEN * sizeof(float), stream);
  hipMemsetAsync((char*)d_ws + (size_t)3 * BATCH * HIDDEN * sizeof(float),
                 0, 4096, stream);

  lstm_persistent<<<dim3(NBLK), dim3(NTHR), 0, stream>>>(
      ids, emb, Wf, bf, Wi, bi, Wo, bo, Wc, bc, fcw, fcb,
      (float*)d_out, (float*)d_ws);
}